// Round 4
// baseline (397.754 us; speedup 1.0000x reference)
//
#include <hip/hip_runtime.h>

// NCC forces, 256^3 fp32, 5x5x5 zero-padded box window, symmetric gradients.
// v4: LDS-pipe diet. v3 counters showed ~85-88% LDS-pipe occupancy (modeled
//     1020 cyc/step/block vs 139us measured), HBM 36%, VALU 44%, occupancy
//     unchanged by grid growth -> LDS instruction count is the limiter.
//     Change: I/R interleaved as float2 cells in one raw ring rawIR[5][12][42]
//     (336B rows, 16B aligned):
//       - B reads: one ds_read_b128 per row covers both columns of the pair
//         for BOTH fields (20 scalar b32 -> 5 b128 per thread).
//       - D gradients / center pipe: (I,R) pairs via single ds_read_b64.
//       - A commit: 8B+8B global loads, one interleaved ds_write_b128.
//     Everything else (single barrier/step, ring discipline, ytmp layout,
//     5x unroll, ZCH=32) identical to v3.
//
// Ring-slot safety (slot(p) = (p - z0 + 10) % 5, K = i % 5): unchanged from
// v3 -- A_{i+1} writes slot K; in-window readers touch K+1,K+2 (D_i) and
// K+4 (B_{i+1}); slot K+1 (= plane zc) is only overwritten at A_{i+2}.

#define DIM  256
#define TX   32
#define TY   8
#define ZCH  32
#define PXA2 42   // raw ring x-stride in float2 cells: 336B rows, 16B aligned
#define PY   12
#define NT   256
#define RS   5
#define YW   40
#define NF   5

#define LDS_BAR() asm volatile("s_waitcnt lgkmcnt(0)\n\ts_barrier" ::: "memory")

#define STEP(K, I, ISSUE, COMMIT) do {                                         \
    constexpr int sZ   = ((K) + 3) % RS;                                       \
    constexpr int sZP  = ((K) + 4) % RS;                                       \
    constexpr int sZM1 = ((K) + 2) % RS;                                       \
    constexpr int sZM2 = ((K) + 1) % RS;                                       \
    const int i_ = (I);                                                        \
    /* A: commit prefetched plane z+1 (interleaved), issue loads of z+2 */     \
    if (pfAct) {                                                               \
        if (COMMIT) {                                                          \
            *(float4*)&rawIR[sZP][prow][pcell] =                               \
                make_float4(pfi.x, pfr.x, pfi.y, pfr.y);                       \
        }                                                                      \
        if (ISSUE) {                                                           \
            float2 vi = make_float2(0.f, 0.f), vr = make_float2(0.f, 0.f);     \
            if ((z0 + i_) < DIM && pxyOk) {                                    \
                vi = *(const float2*)pcurI;                                    \
                vr = *(const float2*)pcurR;                                    \
            }                                                                  \
            pcurI += (size_t)(DIM * DIM);                                      \
            pcurR += (size_t)(DIM * DIM);                                      \
            pfi = vi; pfr = vr;                                                \
        }                                                                      \
    }                                                                          \
    const int b_ = i_ & 1;                                                     \
    /* B: y-direction 5-wide box sums, one b128 per row covers both cols */    \
    if (bAct) {                                                                \
        float sA0=0.f,sA1=0.f,sB0=0.f,sB1=0.f,sAA0=0.f,sAA1=0.f;               \
        float sBB0=0.f,sBB1=0.f,sAB0=0.f,sAB1=0.f;                             \
        _Pragma("unroll")                                                      \
        for (int dy = 0; dy < 5; ++dy) {                                       \
            const float4 v = *(const float4*)&rawIR[sZ][brow + dy][bcol];      \
            sA0 += v.x; sB0 += v.y; sA1 += v.z; sB1 += v.w;                    \
            sAA0 = fmaf(v.x, v.x, sAA0); sBB0 = fmaf(v.y, v.y, sBB0);          \
            sAB0 = fmaf(v.x, v.y, sAB0);                                       \
            sAA1 = fmaf(v.z, v.z, sAA1); sBB1 = fmaf(v.w, v.w, sBB1);          \
            sAB1 = fmaf(v.z, v.w, sAB1);                                       \
        }                                                                      \
        float* yp_ = &ytmp[b_][brow][bcol][0];                                 \
        yp_[0] = sA0; yp_[1] = sB0; yp_[2] = sAA0; yp_[3] = sBB0;              \
        yp_[4] = sAB0;                                                         \
        yp_[5] = sA1; yp_[6] = sB1; yp_[7] = sAA1; yp_[8] = sBB1;              \
        yp_[9] = sAB1;                                                         \
    }                                                                          \
    LDS_BAR();                                                                 \
    /* C: x-direction box sums -- 25 consecutive floats, one base vaddr */     \
    float n_[NF];                                                              \
    {                                                                          \
        const float* yb_ = &ytmp[b_][ty][tx + 2][0];                           \
        _Pragma("unroll")                                                      \
        for (int f = 0; f < NF; ++f)                                           \
            n_[f] = yb_[f] + yb_[f+5] + yb_[f+10] + yb_[f+15] + yb_[f+20];     \
    }                                                                          \
    /* center register pipeline: push plane z-1 (one b64) */                   \
    {                                                                          \
        const float2 c_ = rawIR[sZM1][ly][lx];                                 \
        cIm = cI0; cI0 = cIp; cIp = c_.x;                                      \
        cRm = cR0; cR0 = cRp; cRp = c_.y;                                      \
    }                                                                          \
    /* D: finalize output plane zc = z-2 */                                    \
    if (i_ >= 4) {                                                             \
        const int zc = z0 - 4 + i_;                                            \
        float zs[NF];                                                          \
        _Pragma("unroll")                                                      \
        for (int f = 0; f < NF; ++f)                                           \
            zs[f] = H[((K)+1)%RS][f] + H[((K)+2)%RS][f] + H[((K)+3)%RS][f]     \
                  + H[((K)+4)%RS][f] + n_[f];                                  \
        const float m     = zs[0] * (1.0f / 125.0f);                           \
        const float var_r = zs[3] - 2.0f * m * zs[1] + 125.0f * m * m;         \
        const float var_i = zs[2] - 2.0f * m * zs[0] + 125.0f * m * m;         \
        const float cross = zs[4] - m * zs[0] - m * zs[1] + 125.0f * m * m;    \
        float giz, grz;                                                        \
        if (zc == 0)            { giz = cIp - cI0; grz = cRp - cR0; }          \
        else if (zc == DIM - 1) { giz = cI0 - cIm; grz = cR0 - cRm; }          \
        else { giz = 0.5f * (cIp - cIm); grz = 0.5f * (cRp - cRm); }           \
        const float2 cyp = rawIR[sZM2][ly + 1][lx];                            \
        const float2 cym = rawIR[sZM2][ly - 1][lx];                            \
        const float2 cxp = rawIR[sZM2][ly][lx + 1];                            \
        const float2 cxm = rawIR[sZM2][ly][lx - 1];                            \
        float giy, gry;                                                        \
        if (gy == 0)            { giy = cyp.x - cI0; gry = cyp.y - cR0; }      \
        else if (gy == DIM - 1) { giy = cI0 - cym.x; gry = cR0 - cym.y; }      \
        else { giy = 0.5f * (cyp.x - cym.x); gry = 0.5f * (cyp.y - cym.y); }   \
        float gix, grx;                                                        \
        if (gx == 0)            { gix = cxp.x - cI0; grx = cxp.y - cR0; }      \
        else if (gx == DIM - 1) { gix = cI0 - cxm.x; grx = cR0 - cxm.y; }      \
        else { gix = 0.5f * (cxp.x - cxm.x); grx = 0.5f * (cxp.y - cxm.y); }   \
        const float inv_d = __builtin_amdgcn_rcpf(fmaf(var_i, var_r, 1e-6f));  \
        const float inv_r = __builtin_amdgcn_rcpf(var_r);                      \
        const float factor = 2.0f * cross * inv_d * (cI0 - cross * inv_r * cR0);\
        const size_t CS    = (size_t)DIM * DIM * DIM;                          \
        const size_t base_ = ((size_t)zc * DIM + gy) * DIM + gx;               \
        __builtin_nontemporal_store(-factor * 0.5f * (giz + grz),              \
                                    &gOut[base_]);                             \
        __builtin_nontemporal_store(-factor * 0.5f * (giy + gry),              \
                                    &gOut[base_ + CS]);                        \
        __builtin_nontemporal_store(-factor * 0.5f * (gix + grx),              \
                                    &gOut[base_ + 2 * CS]);                    \
    }                                                                          \
    /* static circular z-history: no shift movs */                             \
    _Pragma("unroll")                                                          \
    for (int f = 0; f < NF; ++f) H[(K)][f] = n_[f];                            \
} while (0)

__global__ __launch_bounds__(NT, 4) void ncc_forces_kernel(
    const float* __restrict__ gI,
    const float* __restrict__ gR,
    float* __restrict__ gOut)
{
    __shared__ __align__(16) float2 rawIR[RS][PY][PXA2];  // (I,R) interleaved
    __shared__ float ytmp[2][TY][YW][NF];   // [buf][y][x][field], x-stride 5

    const int t  = threadIdx.x;
    const int tx = t & 31;
    const int ty = t >> 5;
    const int x0 = blockIdx.x * TX;
    const int y0 = blockIdx.y * TY;
    const int z0 = blockIdx.z * ZCH;

    // staging role: threads 0..239, each owns 2 adjacent cells of the
    // 12x40-cell halo plane; loads 8B from I and 8B from R, writes one
    // interleaved 16B (I0,R0,I1,R1).
    const bool pfAct = (t < 240);
    const int  prow  = t / 20;
    const int  pcell = (t - prow * 20) * 2;          // 0,2,..,38
    const int  pgy   = y0 - 2 + prow;
    const int  pgx   = x0 - 4 + pcell;
    const bool pxyOk = ((unsigned)pgy < DIM) && ((unsigned)pgx < DIM);
    const size_t pgoff = pxyOk ? ((size_t)pgy * DIM + pgx) : 0;

    // y-box role: 144 threads, column pairs covering cells 2..37
    const bool bAct = (t < 144);
    const int  brow = t / 18;
    const int  bcol = 2 + (t - brow * 18) * 2;       // even -> 16B aligned

    const int gy = y0 + ty;
    const int gx = x0 + tx;
    const int ly = ty + 2, lx = tx + 4;

    float2 pfi = make_float2(0.f, 0.f), pfr = make_float2(0.f, 0.f);
    const float* pcurI = gI + (size_t)z0 * (DIM * DIM) + pgoff;
    const float* pcurR = gR + (size_t)z0 * (DIM * DIM) + pgoff;

    float H[RS][NF];
    #pragma unroll
    for (int a = 0; a < RS; ++a)
        #pragma unroll
        for (int f = 0; f < NF; ++f) H[a][f] = 0.f;
    float cIm = 0.f, cI0 = 0.f, cIp = 0.f, cRm = 0.f, cR0 = 0.f, cRp = 0.f;

    // prologue: plane z0-2 direct to slot 3; plane z0-1 into regs
    if (pfAct) {
        float2 vi = make_float2(0.f, 0.f), vr = make_float2(0.f, 0.f);
        if ((z0 - 2) >= 0 && pxyOk) {
            vi = *(const float2*)(gI + (size_t)(z0 - 2) * (DIM * DIM) + pgoff);
            vr = *(const float2*)(gR + (size_t)(z0 - 2) * (DIM * DIM) + pgoff);
        }
        *(float4*)&rawIR[3][prow][pcell] = make_float4(vi.x, vr.x, vi.y, vr.y);
        float2 wi = make_float2(0.f, 0.f), wr = make_float2(0.f, 0.f);
        if ((z0 - 1) >= 0 && pxyOk) {
            wi = *(const float2*)(gI + (size_t)(z0 - 1) * (DIM * DIM) + pgoff);
            wr = *(const float2*)(gR + (size_t)(z0 - 1) * (DIM * DIM) + pgoff);
        }
        pfi = wi; pfr = wr;
    }
    LDS_BAR();

    // 36 steps total: 6x5 main + 6-step tail with static slots
    #pragma clang loop unroll(disable)
    for (int ii = 0; ii < 30; ii += 5) {
        STEP(0, ii + 0, true, true);
        STEP(1, ii + 1, true, true);
        STEP(2, ii + 2, true, true);
        STEP(3, ii + 3, true, true);
        STEP(4, ii + 4, true, true);
    }
    STEP(0, 30, true,  true);
    STEP(1, 31, true,  true);
    STEP(2, 32, true,  true);
    STEP(3, 33, true,  true);   // issues plane z0+33, last one B needs (i=35)
    STEP(4, 34, false, true);   // commits z0+33; no more loads
    STEP(0, 35, false, false);  // last output plane zc = z0+31
}

extern "C" void kernel_launch(void* const* d_in, const int* in_sizes, int n_in,
                              void* d_out, int out_size, void* d_ws, size_t ws_size,
                              hipStream_t stream) {
    const float* img = (const float*)d_in[0];  // image
    const float* ref = (const float*)d_in[2];  // reference_image
    float* out = (float*)d_out;

    dim3 grid(DIM / TX, DIM / TY, DIM / ZCH);  // 8 x 32 x 8 = 2048 blocks
    ncc_forces_kernel<<<grid, NT, 0, stream>>>(img, ref, out);
}